// Round 10
// baseline (1673.523 us; speedup 1.0000x reference)
//
#include <hip/hip_runtime.h>
#include <stdint.h>

// LSTM_Trend: B=256, T=512, F=64, H=512, P=24.
// Persistent kernel: 256 WGs x 256 threads (1/CU) = 16 batch-groups x 16
// hidden-groups. Weights register-resident as MFMA B-fragments.
//
// R10: WAVE-AUTONOMOUS STEP -- ZERO barriers in the T-loop.
// R5-R9 showed the ~2us/step cost is structural: every step crossed 2-4
// __syncthreads + a WG-shared LDS round trip, paying 1024-thread straggler
// max per leg, with 1 wave/SIMD (nothing covers bubbles). Here each wave is
// self-sufficient:
//  - h A-frags: lane (nl,kq) ld128s its 16 fragments straight from the
//    packed h layout in the XCD L2 (R7-proven pattern; transport = R4's
//    verified XCD-local sc0 stores + sc0sc1 loads hitting dirty L2 lines).
//  - act is WAVE-LOCAL: wave wv computes gate cols [wv*32,+32) = units
//    [wv*8,+8) of the WG's 32-unit span, and acts on exactly those units.
//    Gate scatter->gather goes through a wave-private LDS slice Gw[wv]
//    (stride 36 floats: 16B-aligned f32x4 reads, 2-way banks) -- same-wave
//    LDS is ordered by lgkmcnt alone, NO barrier.
//  - h store + per-wave flag: wave-local (store, wave vmcnt(0), lane0 flag).
//  - the ONLY join: 64-flag poll, lane ln polls flag[ln] (one coalesced
//    wave load per retry round).
// Flag semantics: value v = "h for iteration v-1's consumers" ready, i.e.
// iteration t polls all 64 flags >= t+1, then loads h(t) from parity t&1;
// act(t) stores h(t+1) to parity (t+1)&1, drains, publishes t+2. Overwrite
// safety: act(t) overwrites h(t-1); producer saw all flags >= t+1, and a
// flag t+1 is published only after that wave finished its iteration-(t-1)
// loads of h(t-1). Prologue: zero parity 0, drain, publish flag 1.
// rule #18: sched_barrier(0) after every inline-asm waitcnt whose consumers
// are register-only (poll compares, h-MFMA blocks, FC MFMAs).
// Fallback (rendezvous popcount!=1): sc0sc1 stores, correct anywhere.

namespace {
constexpr int T_STEPS = 512;
constexpr int FEA  = 64;
constexpr int HID  = 512;
constexpr int NKI  = 18;          // 16 h k-iters + 2 x k-iters
constexpr int GWS  = 36;          // Gw row stride (floats): 16B-aligned reads
constexpr size_t HBUF_DW  = 256ull * 256;       // packed h dwords per parity
constexpr size_t FLAG_OFF = 2 * HBUF_DW;        // 16 groups x 64 wave-flags
constexpr size_t GRZ_OFF  = FLAG_OFF + 16 * 64; // gmask[16], gcnt[16]

typedef __bf16   bf16x8 __attribute__((ext_vector_type(8)));
typedef uint16_t u16x8  __attribute__((ext_vector_type(8)));
typedef float    f32x4  __attribute__((ext_vector_type(4)));
typedef uint32_t u32x4  __attribute__((ext_vector_type(4)));

union V8 { u16x8 u; bf16x8 b; u32x4 q; };

__device__ __forceinline__ float bf2f(uint16_t u) {
  union { uint32_t i; float f; } v; v.i = (uint32_t)u << 16; return v.f;
}
__device__ __forceinline__ uint16_t f2bf(float f) {
  union { float f; uint32_t i; } v; v.f = f;
  uint32_t x = v.i;
  return (uint16_t)((x + 0x7FFFu + ((x >> 16) & 1u)) >> 16);  // RNE
}
__device__ __forceinline__ float sigmoid_f(float x) {
  return 1.0f / (1.0f + __expf(-x));
}
__device__ __forceinline__ float tanh_f(float x) {
  float e = __expf(-2.0f * fabsf(x));
  float t = (1.0f - e) / (1.0f + e);
  return copysignf(t, x);
}
__device__ __forceinline__ bf16x8 load8(const void* base, size_t elem_off,
                                        bool fp32m) {
  V8 r;
  if (fp32m) {
    const float* p = (const float*)base + elem_off;
#pragma unroll
    for (int i = 0; i < 8; ++i) r.u[i] = f2bf(p[i]);
  } else {
    r.q = *(const u32x4*)((const uint16_t*)base + elem_off);
  }
  return r.b;
}
__device__ __forceinline__ float loadf(const void* base, int idx, bool fp32m) {
  return fp32m ? ((const float*)base)[idx] : bf2f(((const uint16_t*)base)[idx]);
}

// ---- exchange memory ops (transport proven in R4) -------------------------
__device__ __forceinline__ uint32_t ld32_sc01(const uint32_t* p) {
  uint32_t v;
  asm volatile("global_load_dword %0, %1, off sc0 sc1"
               : "=v"(v) : "v"(p) : "memory");
  return v;
}
__device__ __forceinline__ u32x4 ld128_sc01(const uint32_t* p) {
  u32x4 v;
  asm volatile("global_load_dwordx4 %0, %1, off sc0 sc1"
               : "=v"(v) : "v"(p) : "memory");
  return v;
}
__device__ __forceinline__ void st32_x(uint32_t* p, uint32_t v, bool xl) {
  if (xl) asm volatile("global_store_dword %0, %1, off sc0"
                       :: "v"(p), "v"(v) : "memory");
  else    asm volatile("global_store_dword %0, %1, off sc0 sc1"
                       :: "v"(p), "v"(v) : "memory");
}
__device__ __forceinline__ void st128_x(uint32_t* p, u32x4 v, bool xl) {
  if (xl) asm volatile("global_store_dwordx4 %0, %1, off sc0"
                       :: "v"(p), "v"(v) : "memory");
  else    asm volatile("global_store_dwordx4 %0, %1, off sc0 sc1"
                       :: "v"(p), "v"(v) : "memory");
}
__device__ __forceinline__ void waitcnt_vm0() {
  asm volatile("s_waitcnt vmcnt(0)" ::: "memory");
}
// rule #18: register-only consumers (compares/MFMA) get hoisted past an
// inline-asm waitcnt; sched_barrier(0) pins them.
__device__ __forceinline__ void waitcnt_vm0_fence() {
  asm volatile("s_waitcnt vmcnt(0)" ::: "memory");
  __builtin_amdgcn_sched_barrier(0);
}
} // namespace

__global__ __launch_bounds__(256, 1) void lstm_persistent(
    const void* __restrict__ x,      // [256][512][64]
    const void* __restrict__ W_ih,   // [2048][64]
    const void* __restrict__ W_hh,   // [2048][512]
    const void* __restrict__ b_ih,   // [2048]
    const void* __restrict__ b_hh,   // [2048]
    const void* __restrict__ W_fc,   // [1536][512]
    const void* __restrict__ b_fc,   // [1536]
    void* __restrict__ out,          // [256][1536]
    uint32_t* __restrict__ dbuf)     // ws: [2][256][256] h + flags + rdzv
{
  __shared__ float Gw[4][16 * GWS];     // wave-private gate slices
  __shared__ int   sflag, sok;

  const int tid = threadIdx.x;
  const int wv  = tid >> 6;              // wave 0..3
  const int ln  = tid & 63;
  const int nl  = ln & 15;               // MFMA m/n lane index (row)
  const int kq  = ln >> 4;               // MFMA k-quad
  const int bg  = blockIdx.x & 15;       // batch group
  const int wgi = blockIdx.x >> 4;       // hidden group 0..15
  const int r0  = bg * 16;               // first batch row of this group

  // ---- per-group XCD-identity rendezvous (one-time, R4-proven) ------------
  if (tid == 0) {
    uint32_t xcc;
    asm volatile("s_getreg_b32 %0, hwreg(HW_REG_XCC_ID)" : "=s"(xcc));
    unsigned* gmask = (unsigned*)(dbuf + GRZ_OFF) + bg;
    unsigned* gcnt  = (unsigned*)(dbuf + GRZ_OFF) + 16 + bg;
    atomicOr(gmask, 1u << (xcc & 31));
    __threadfence();
    atomicAdd(gcnt, 1u);
    while (atomicAdd(gcnt, 0u) < 16u) __builtin_amdgcn_s_sleep(1);
    __threadfence();
    unsigned m = atomicOr(gmask, 0u);
    sok = (__popc(m) == 1) ? 1 : 0;
  }

  // ---- dtype sniff (block-uniform): fp32 read as bf16 -> huge exponents
  if (tid == 1) sflag = 0;
  __syncthreads();
  {
    float a = fabsf(bf2f(((const uint16_t*)b_ih)[tid]));
    if (a > 1.0f) atomicOr(&sflag, 1);
  }
  __syncthreads();
  const bool fp32m = (sflag != 0);
  const bool xloc  = (sok != 0);

  // wave owns cols [wv*32, wv*32+32) as two 16-col subtiles sharing one A-frag
  bf16x8 breg[2][NKI];
  float  bias[2];
#pragma unroll
  for (int s = 0; s < 2; ++s) {
    int col  = wv * 32 + s * 16 + nl;    // 0..127
    int gate = col & 3;
    int unit = col >> 2;                 // 0..31 (WG-local)
    int gcol = gate * HID + wgi * 32 + unit;
#pragma unroll
    for (int kk = 0; kk < NKI; ++kk) {
      int k0 = kk * 32 + kq * 8;
      if (k0 < HID)
        breg[s][kk] = load8(W_hh, (size_t)gcol * HID + k0, fp32m);
      else
        breg[s][kk] = load8(W_ih, (size_t)gcol * FEA + (k0 - HID), fp32m);
    }
    bias[s] = loadf(b_ih, gcol, fp32m) + loadf(b_hh, gcol, fp32m);
  }

  // wave-local act roles: row arow (0..15), unit-pair up (0..3)
  // wave wv acts on WG-local units u0 = wv*8 + up*2, u0+1 for all 16 rows.
  const int arow = ln >> 2;
  const int up   = ln & 3;
  const int hdw  = (r0 + arow) * 256 + wgi * 16 + wv * 4 + up;
  float c0 = 0.0f, c1 = 0.0f;

  uint32_t* flagw = dbuf + FLAG_OFF + bg * 64 + wgi * 4 + wv;   // producer
  const uint32_t* fbase = dbuf + FLAG_OFF + bg * 64;            // lane ln polls [ln]

  // ---- prologue: zero h parity 0 for this group; publish flag = 1 ----
  {
    uint32_t* p0 = dbuf + (size_t)(r0 + (tid >> 4)) * 256 + (tid & 15) * 16;
    u32x4 z = {0, 0, 0, 0};
#pragma unroll
    for (int i = 0; i < 4; ++i) st128_x(p0 + i * 4, z, xloc);
    waitcnt_vm0();
    if (ln == 0) st32_x(flagw, 1u, xloc);
  }

  for (int t = 0; t < T_STEPS; ++t) {
    const uint32_t tgt = (uint32_t)(t + 1);

    // ---- x A-frags (plain cached loads; issued before poll, drain covers) --
    size_t xoff = (size_t)(r0 + nl) * (T_STEPS * FEA) + (size_t)t * FEA
                + kq * 8;
    bf16x8 ax0 = load8(x, xoff, fp32m);
    bf16x8 ax1 = load8(x, xoff + 32, fp32m);

    // ---- the ONLY join: lane ln polls wave-flag ln >= t+1 ----
    for (;;) {
      uint32_t f = ld32_sc01(fbase + ln);
      waitcnt_vm0_fence();               // fence: compare is register-only
      if (f >= tgt) break;
      __builtin_amdgcn_s_sleep(1);
    }

    // ---- h A-frags: 16 x ld128 straight from the packed L2 layout ----
    const uint32_t* hb = dbuf + (size_t)(t & 1) * HBUF_DW
                       + (size_t)(r0 + nl) * 256 + kq * 4;
    V8 av[16];
#pragma unroll
    for (int p = 0; p < 16; ++p) av[p].q = ld128_sc01(hb + p * 16);

    // ---- x MFMAs while h loads are in flight ----
    f32x4 c0a, c0b, c1a, c1b;
#pragma unroll
    for (int i = 0; i < 4; ++i) {
      c0a[i] = bias[0]; c1a[i] = bias[1]; c0b[i] = 0.0f; c1b[i] = 0.0f;
    }
    c0a = __builtin_amdgcn_mfma_f32_16x16x32_bf16(ax0, breg[0][16], c0a, 0, 0, 0);
    c1a = __builtin_amdgcn_mfma_f32_16x16x32_bf16(ax0, breg[1][16], c1a, 0, 0, 0);
    c0b = __builtin_amdgcn_mfma_f32_16x16x32_bf16(ax1, breg[0][17], c0b, 0, 0, 0);
    c1b = __builtin_amdgcn_mfma_f32_16x16x32_bf16(ax1, breg[1][17], c1b, 0, 0, 0);
    waitcnt_vm0_fence();                 // fence: h-MFMAs are register-only

    // ---- 32 h MFMAs, 4 accumulator chains ----
#pragma unroll
    for (int kk = 0; kk < 16; ++kk) {
      if (kk & 1) {
        c0b = __builtin_amdgcn_mfma_f32_16x16x32_bf16(av[kk].b, breg[0][kk], c0b, 0, 0, 0);
        c1b = __builtin_amdgcn_mfma_f32_16x16x32_bf16(av[kk].b, breg[1][kk], c1b, 0, 0, 0);
      } else {
        c0a = __builtin_amdgcn_mfma_f32_16x16x32_bf16(av[kk].b, breg[0][kk], c0a, 0, 0, 0);
        c1a = __builtin_amdgcn_mfma_f32_16x16x32_bf16(av[kk].b, breg[1][kk], c1a, 0, 0, 0);
      }
    }
    f32x4 A0 = c0a + c0b, A1 = c1a + c1b;

    // ---- gate scatter -> wave-private Gw (same-wave LDS, lgkmcnt only) ----
    float* G = &Gw[wv][0];
#pragma unroll
    for (int r = 0; r < 4; ++r) {
      G[(kq * 4 + r) * GWS + nl]      = A0[r];
      G[(kq * 4 + r) * GWS + 16 + nl] = A1[r];
    }

    // ---- act gather (compiler inserts lgkmcnt wait; same wave) ----
    {
      const float* gp = &Gw[wv][arow * GWS + up * 8];
      f32x4 ga = *(const f32x4*)gp;
      f32x4 gb = *(const f32x4*)(gp + 4);
      c0 = sigmoid_f(ga[1]) * c0 + sigmoid_f(ga[0]) * tanh_f(ga[2]);
      float h0 = sigmoid_f(ga[3]) * tanh_f(c0);
      c1 = sigmoid_f(gb[1]) * c1 + sigmoid_f(gb[0]) * tanh_f(gb[2]);
      float h1 = sigmoid_f(gb[3]) * tanh_f(c1);
      uint32_t hp = (uint32_t)f2bf(h0) | ((uint32_t)f2bf(h1) << 16);
      st32_x(dbuf + (size_t)((t + 1) & 1) * HBUF_DW + hdw, hp, xloc);
      waitcnt_vm0();                     // wave's h store at L2
      if (ln == 0) st32_x(flagw, (uint32_t)(t + 2), xloc);
    }
  }

  // ---- FC head: out = h_T @ W_fc^T + b_fc  (h_T in parity 0, flags 513) ---
  for (;;) {
    uint32_t f = ld32_sc01(fbase + ln);
    waitcnt_vm0_fence();
    if (f >= (uint32_t)(T_STEPS + 1)) break;
    __builtin_amdgcn_s_sleep(1);
  }
  int gwave = wgi * 4 + wv;              // 0..63 within the batch group
  for (int tile = gwave; tile < 96; tile += 64) {
    int n = tile * 16 + nl;              // out column
    float bs = loadf(b_fc, n, fp32m);
    f32x4 acc; acc[0] = bs; acc[1] = bs; acc[2] = bs; acc[3] = bs;
    const uint32_t* hb = dbuf + (size_t)(r0 + nl) * 256 + kq * 4;
    V8 av[16];
#pragma unroll
    for (int p = 0; p < 16; ++p) av[p].q = ld128_sc01(hb + p * 16);
    waitcnt_vm0_fence();                 // fence: MFMAs are register-only
#pragma unroll
    for (int kk = 0; kk < 16; ++kk) {
      bf16x8 b = load8(W_fc, (size_t)n * HID + kk * 32 + kq * 8, fp32m);
      acc = __builtin_amdgcn_mfma_f32_16x16x32_bf16(av[kk].b, b, acc, 0, 0, 0);
    }
#pragma unroll
    for (int r = 0; r < 4; ++r) {
      int row = r0 + kq * 4 + r;
      if (fp32m) ((float*)out)[(size_t)row * 1536 + n] = acc[r];
      else       ((uint16_t*)out)[(size_t)row * 1536 + n] = f2bf(acc[r]);
    }
  }
}

extern "C" void kernel_launch(void* const* d_in, const int* in_sizes, int n_in,
                              void* d_out, int out_size, void* d_ws, size_t ws_size,
                              hipStream_t stream) {
  const void* x    = d_in[0];
  const void* W_ih = d_in[1];
  const void* W_hh = d_in[2];
  const void* b_ih = d_in[3];
  const void* b_hh = d_in[4];
  const void* W_fc = d_in[5];
  const void* b_fc = d_in[6];
  uint32_t* dbuf = (uint32_t*)d_ws;

  // flags (16x64 dwords) + rendezvous (gmask[16], gcnt[16]) start at 0 each
  // call (ws is poisoned 0xAA; poisoned gmask -> safe sc0sc1 fallback;
  // flags MUST be zeroed -- poll uses >= and 0xAAAAAAAA would pass).
  hipMemsetAsync((void*)(dbuf + FLAG_OFF), 0,
                 (16 * 64 + 32) * sizeof(uint32_t), stream);

  lstm_persistent<<<dim3(256), dim3(256), 0, stream>>>(
      x, W_ih, W_hh, b_ih, b_hh, W_fc, b_fc, d_out, dbuf);
}

// Round 11
// 1054.596 us; speedup vs baseline: 1.5869x; 1.5869x over previous
//
#include <hip/hip_runtime.h>
#include <stdint.h>

// LSTM_Trend: B=256, T=512, F=64, H=512, P=24.
// Persistent kernel: 256 WGs x 256 threads (1/CU) = 16 batch-groups x 16
// hidden-groups. Weights register-resident as MFMA B-fragments.
//
// R11 = R8 (1033us, best) + FOUR-CHAIN MFMA, single variable.
// Family closed by R5/R7/R9/R10: tagged polls, per-thread fused poll+load,
// and per-lane register-direct L2 fragment loads ALL lose to R8's shape
// (coalesced bulk load -> LDS -> frag reads; 16-lane flag poll; 3 barriers;
// XCD-local sc0 stores verified by rendezvous + sc0sc1 loads hitting dirty
// local-L2 lines -- R4's transport, WRITE_SIZE 137->2 MB).
// The 4-chain split (c0a/c0b/c1a/c1b, halves MFMA dep depth 18->9) was
// numerically validated in R9 but bundled with a regressor; here isolated.
// Flag protocol (R8, proven): act wave stores h(t+1) to parity (t+1)&1,
// drains ITS OWN stores (wave vmcnt(0)), lane 0 publishes flag t+1. Poll:
// 16 lanes x ld128 over the group's 64-flag line, sched_barrier(0) after
// the inline-asm waitcnt (rule #18: compares are register-only). Overwrite
// safety: flag t+2 implies that WG passed S1(t+1), hence finished bulk(t)
// loads; producer observes all flags >= t+2 at poll(t+1) before act(t+2).

namespace {
constexpr int T_STEPS = 512;
constexpr int FEA  = 64;
constexpr int HID  = 512;
constexpr int NKI  = 18;          // 16 h k-iters + 2 x k-iters
constexpr int GSTR = 132;         // gates LDS row stride (floats)
constexpr int RPG  = 16;          // batch rows per group
constexpr int GPITCH = 136;       // uint16 elems per granule (272 B pitch)
constexpr size_t HBUF_DW  = 256ull * 256;       // packed h dwords per parity
constexpr size_t FLAG_OFF = 2 * HBUF_DW;        // 16 groups x 64 wave-flags
constexpr size_t GRZ_OFF  = FLAG_OFF + 16 * 64; // gmask[16], gcnt[16]

typedef __bf16   bf16x8 __attribute__((ext_vector_type(8)));
typedef uint16_t u16x8  __attribute__((ext_vector_type(8)));
typedef float    f32x4  __attribute__((ext_vector_type(4)));
typedef uint32_t u32x4  __attribute__((ext_vector_type(4)));

union V8 { u16x8 u; bf16x8 b; u32x4 q; };

__device__ __forceinline__ float bf2f(uint16_t u) {
  union { uint32_t i; float f; } v; v.i = (uint32_t)u << 16; return v.f;
}
__device__ __forceinline__ uint16_t f2bf(float f) {
  union { float f; uint32_t i; } v; v.f = f;
  uint32_t x = v.i;
  return (uint16_t)((x + 0x7FFFu + ((x >> 16) & 1u)) >> 16);  // RNE
}
__device__ __forceinline__ float sigmoid_f(float x) {
  return 1.0f / (1.0f + __expf(-x));
}
__device__ __forceinline__ float tanh_f(float x) {
  float e = __expf(-2.0f * fabsf(x));
  float t = (1.0f - e) / (1.0f + e);
  return copysignf(t, x);
}
__device__ __forceinline__ bf16x8 load8(const void* base, size_t elem_off,
                                        bool fp32m) {
  V8 r;
  if (fp32m) {
    const float* p = (const float*)base + elem_off;
#pragma unroll
    for (int i = 0; i < 8; ++i) r.u[i] = f2bf(p[i]);
  } else {
    r.q = *(const u32x4*)((const uint16_t*)base + elem_off);
  }
  return r.b;
}
__device__ __forceinline__ float loadf(const void* base, int idx, bool fp32m) {
  return fp32m ? ((const float*)base)[idx] : bf2f(((const uint16_t*)base)[idx]);
}
__device__ __forceinline__ uint2 ldx4(const void* x, size_t elem_off,
                                      bool fp32m) {  // 4 x-vals -> 4 bf16
  if (fp32m) {
    float4 v = *(const float4*)((const float*)x + elem_off);
    uint2 w;
    w.x = (uint32_t)f2bf(v.x) | ((uint32_t)f2bf(v.y) << 16);
    w.y = (uint32_t)f2bf(v.z) | ((uint32_t)f2bf(v.w) << 16);
    return w;
  }
  return *(const uint2*)((const uint16_t*)x + elem_off);
}

// ---- exchange memory ops (transport proven in R4) -------------------------
__device__ __forceinline__ u32x4 ld128_sc01(const uint32_t* p) {
  u32x4 v;
  asm volatile("global_load_dwordx4 %0, %1, off sc0 sc1"
               : "=v"(v) : "v"(p) : "memory");
  return v;
}
__device__ __forceinline__ void st32_x(uint32_t* p, uint32_t v, bool xl) {
  if (xl) asm volatile("global_store_dword %0, %1, off sc0"
                       :: "v"(p), "v"(v) : "memory");
  else    asm volatile("global_store_dword %0, %1, off sc0 sc1"
                       :: "v"(p), "v"(v) : "memory");
}
__device__ __forceinline__ void waitcnt_vm0() {
  asm volatile("s_waitcnt vmcnt(0)" ::: "memory");
}
// rule #18: register-only consumers (compares/MFMA) get hoisted past an
// inline-asm waitcnt; sched_barrier(0) pins them.
__device__ __forceinline__ void waitcnt_vm0_fence() {
  asm volatile("s_waitcnt vmcnt(0)" ::: "memory");
  __builtin_amdgcn_sched_barrier(0);
}
} // namespace

__global__ __launch_bounds__(256, 1) void lstm_persistent(
    const void* __restrict__ x,      // [256][512][64]
    const void* __restrict__ W_ih,   // [2048][64]
    const void* __restrict__ W_hh,   // [2048][512]
    const void* __restrict__ b_ih,   // [2048]
    const void* __restrict__ b_hh,   // [2048]
    const void* __restrict__ W_fc,   // [1536][512]
    const void* __restrict__ b_fc,   // [1536]
    void* __restrict__ out,          // [256][1536]
    uint32_t* __restrict__ dbuf)     // ws: [2][256][256] h + flags + rdzv
{
  __shared__ __align__(16) uint16_t Als[72 * GPITCH];  // frag-major A tile
  __shared__ float Gls[RPG * GSTR];     // gate pre-activations
  __shared__ int   sflag, sok;

  const int tid = threadIdx.x;
  const int wv  = tid >> 6;              // wave 0..3
  const int ln  = tid & 63;
  const int nl  = ln & 15;               // MFMA m/n lane index (row)
  const int kq  = ln >> 4;               // MFMA k-quad
  const int bg  = blockIdx.x & 15;       // batch group
  const int wgi = blockIdx.x >> 4;       // hidden group 0..15
  const int r0  = bg * RPG;              // first batch row of this group

  // ---- per-group XCD-identity rendezvous (one-time, R4-proven) ------------
  if (tid == 0) {
    uint32_t xcc;
    asm volatile("s_getreg_b32 %0, hwreg(HW_REG_XCC_ID)" : "=s"(xcc));
    unsigned* gmask = (unsigned*)(dbuf + GRZ_OFF) + bg;
    unsigned* gcnt  = (unsigned*)(dbuf + GRZ_OFF) + 16 + bg;
    atomicOr(gmask, 1u << (xcc & 31));
    __threadfence();
    atomicAdd(gcnt, 1u);
    while (atomicAdd(gcnt, 0u) < 16u) __builtin_amdgcn_s_sleep(1);
    __threadfence();
    unsigned m = atomicOr(gmask, 0u);
    sok = (__popc(m) == 1) ? 1 : 0;
  }

  // ---- dtype sniff (block-uniform): fp32 read as bf16 -> huge exponents
  if (tid == 1) sflag = 0;
  __syncthreads();
  {
    float a = fabsf(bf2f(((const uint16_t*)b_ih)[tid]));
    if (a > 1.0f) atomicOr(&sflag, 1);
  }
  __syncthreads();
  const bool fp32m = (sflag != 0);
  const bool xloc  = (sok != 0);

  // wave owns cols [wv*32, wv*32+32) as two 16-col subtiles sharing one A-frag
  bf16x8 breg[2][NKI];
  float  bias[2];
#pragma unroll
  for (int s = 0; s < 2; ++s) {
    int col  = wv * 32 + s * 16 + nl;    // 0..127
    int gate = col & 3;
    int unit = col >> 2;                 // 0..31
    int gcol = gate * HID + wgi * 32 + unit;
#pragma unroll
    for (int kk = 0; kk < NKI; ++kk) {
      int k0 = kk * 32 + kq * 8;
      if (k0 < HID)
        breg[s][kk] = load8(W_hh, (size_t)gcol * HID + k0, fp32m);
      else
        breg[s][kk] = load8(W_ih, (size_t)gcol * FEA + (k0 - HID), fp32m);
    }
    bias[s] = loadf(b_ih, gcol, fp32m) + loadf(b_hh, gcol, fp32m);
  }

  // act roles: row ar (0..15), units au, au+1; wave wv covers ar = 4wv..4wv+3
  const int ar  = tid >> 4;
  const int au  = (tid & 15) * 2;
  const int hdw = (r0 + ar) * 256 + wgi * 16 + (tid & 15);  // packed h dword
  float c0 = 0.0f, c1 = 0.0f;

  // staging roles: row = tid>>4, class sc = tid&15
  const int srow = tid >> 4;
  const int sc   = tid & 15;

  uint32_t* flagw = dbuf + FLAG_OFF + bg * 64 + wgi * 4 + wv;   // producer
  // consumer: lane i (i<16) checks producer i's 4 wave-flags via one ld128
  const uint32_t* fb0 = dbuf + FLAG_OFF + bg * 64;

  // ---- prologue: h(0)=0 in LDS (granules 0..63), stage x(0) ----
  {
    u32x4 z = {0, 0, 0, 0};
    for (int i = tid; i < 64 * GPITCH / 8; i += 256)
      *(u32x4*)&Als[i * 8] = z;
  }
  {
    int gx = sc & 7, hf = sc >> 3;
    size_t off = (size_t)(r0 + srow) * (T_STEPS * FEA) + gx * 8 + hf * 4;
    uint2 w = ldx4(x, off, fp32m);
    *(uint2*)&Als[(64 + gx) * GPITCH + srow * 8 + hf * 4] = w;
  }

  for (int t = 0; t < T_STEPS; ++t) {
    __syncthreads();                     // S1: A tile staged

    // ---- gates = A @ W^T + bias: 18 k-iters, FOUR accumulator chains ----
    f32x4 c0a, c0b, c1a, c1b;
#pragma unroll
    for (int i = 0; i < 4; ++i) {
      c0a[i] = bias[0]; c1a[i] = bias[1]; c0b[i] = 0.0f; c1b[i] = 0.0f;
    }
#pragma unroll
    for (int kk = 0; kk < NKI; ++kk) {
      bf16x8 a = *(const bf16x8*)&Als[(4 * kk + kq) * GPITCH + nl * 8];
      if (kk & 1) {
        c0b = __builtin_amdgcn_mfma_f32_16x16x32_bf16(a, breg[0][kk], c0b, 0, 0, 0);
        c1b = __builtin_amdgcn_mfma_f32_16x16x32_bf16(a, breg[1][kk], c1b, 0, 0, 0);
      } else {
        c0a = __builtin_amdgcn_mfma_f32_16x16x32_bf16(a, breg[0][kk], c0a, 0, 0, 0);
        c1a = __builtin_amdgcn_mfma_f32_16x16x32_bf16(a, breg[1][kk], c1a, 0, 0, 0);
      }
    }
    f32x4 A0 = c0a + c0b, A1 = c1a + c1b;
#pragma unroll
    for (int r = 0; r < 4; ++r) {
      Gls[(kq * 4 + r) * GSTR + wv * 32 + nl]      = A0[r];
      Gls[(kq * 4 + r) * GSTR + wv * 32 + 16 + nl] = A1[r];
    }
    __syncthreads();                     // S2: gates ready, A tile free

    const uint32_t tg = (uint32_t)(t + 1);
    const bool havex = (t + 1 < T_STEPS);

    // ---- act: cell update; h store; WAVE drain; per-wave flag ----
    {
      const f32x4* gp = (const f32x4*)&Gls[ar * GSTR + au * 4];
      f32x4 ga = gp[0], gb = gp[1];
      c0 = sigmoid_f(ga[1]) * c0 + sigmoid_f(ga[0]) * tanh_f(ga[2]);
      float h0 = sigmoid_f(ga[3]) * tanh_f(c0);
      c1 = sigmoid_f(gb[1]) * c1 + sigmoid_f(gb[0]) * tanh_f(gb[2]);
      float h1 = sigmoid_f(gb[3]) * tanh_f(c1);
      uint32_t hp = (uint32_t)f2bf(h0) | ((uint32_t)f2bf(h1) << 16);
      st32_x(dbuf + (size_t)(tg & 1) * HBUF_DW + hdw, hp, xloc);
      waitcnt_vm0();                     // this wave's h stores at L2
      if (ln == 0) st32_x(flagw, tg, xloc);
    }

    // ---- stage x(t+1) (x region free after S2; overlaps flag latency) ----
    if (havex) {
      int gx = sc & 7, hf = sc >> 3;
      size_t off = (size_t)(r0 + srow) * (T_STEPS * FEA)
                 + (size_t)(t + 1) * FEA + gx * 8 + hf * 4;
      uint2 w = ldx4(x, off, fp32m);
      *(uint2*)&Als[(64 + gx) * GPITCH + srow * 8 + hf * 4] = w;
    }

    // ---- poll: 16 lanes, one ld128 of 4 wave-flags each ----
    if (tid < 16) {
      const uint32_t* fp = fb0 + tid * 4;
      for (;;) {
        u32x4 f = ld128_sc01(fp);
        waitcnt_vm0_fence();             // fence: compares are register-only
        uint32_t mn = f[0];
        mn = f[1] < mn ? f[1] : mn;
        mn = f[2] < mn ? f[2] : mn;
        mn = f[3] < mn ? f[3] : mn;
        if (mn >= tg) break;
      }
    }
    __syncthreads();                     // S3: all h(t+1) visible in L2

    // ---- bulk h(t+1) -> frag-major LDS (coalesced global, cf writes) ----
    if (havex) {
      const uint32_t* src = dbuf + (size_t)(tg & 1) * HBUF_DW
                          + (size_t)(r0 + srow) * 256;
      u32x4 v0 = ld128_sc01(src + (sc + 0)  * 4);
      u32x4 v1 = ld128_sc01(src + (sc + 16) * 4);
      u32x4 v2 = ld128_sc01(src + (sc + 32) * 4);
      u32x4 v3 = ld128_sc01(src + (sc + 48) * 4);
      waitcnt_vm0();                     // LDS writes below (memory-ordered)
      *(u32x4*)&Als[(sc + 0)  * GPITCH + srow * 8] = v0;
      *(u32x4*)&Als[(sc + 16) * GPITCH + srow * 8] = v1;
      *(u32x4*)&Als[(sc + 32) * GPITCH + srow * 8] = v2;
      *(u32x4*)&Als[(sc + 48) * GPITCH + srow * 8] = v3;
    }
  }

  // ---- FC head: out = h_T @ W_fc^T + b_fc  (h_T in parity 0, flags>=512) --
  int gwave = wgi * 4 + wv;              // 0..63 within the batch group
  for (int tile = gwave; tile < 96; tile += 64) {
    int n = tile * 16 + nl;              // out column
    float bs = loadf(b_fc, n, fp32m);
    f32x4 acc; acc[0] = bs; acc[1] = bs; acc[2] = bs; acc[3] = bs;
    const uint32_t* hb = dbuf + (size_t)(r0 + nl) * 256 + kq * 4;
    V8 av[16];
#pragma unroll
    for (int p = 0; p < 16; ++p) av[p].q = ld128_sc01(hb + p * 16);
    waitcnt_vm0_fence();                 // fence: MFMAs are register-only
#pragma unroll
    for (int kk = 0; kk < 16; ++kk) {
      bf16x8 b = load8(W_fc, (size_t)n * HID + kk * 32 + kq * 8, fp32m);
      acc = __builtin_amdgcn_mfma_f32_16x16x32_bf16(av[kk].b, b, acc, 0, 0, 0);
    }
#pragma unroll
    for (int r = 0; r < 4; ++r) {
      int row = r0 + kq * 4 + r;
      if (fp32m) ((float*)out)[(size_t)row * 1536 + n] = acc[r];
      else       ((uint16_t*)out)[(size_t)row * 1536 + n] = f2bf(acc[r]);
    }
  }
}

extern "C" void kernel_launch(void* const* d_in, const int* in_sizes, int n_in,
                              void* d_out, int out_size, void* d_ws, size_t ws_size,
                              hipStream_t stream) {
  const void* x    = d_in[0];
  const void* W_ih = d_in[1];
  const void* W_hh = d_in[2];
  const void* b_ih = d_in[3];
  const void* b_hh = d_in[4];
  const void* W_fc = d_in[5];
  const void* b_fc = d_in[6];
  uint32_t* dbuf = (uint32_t*)d_ws;

  // flags (16x64 dwords) + rendezvous (gmask[16], gcnt[16]) start at 0 each
  // call (ws is poisoned 0xAA; poisoned gmask -> safe sc0sc1 fallback).
  hipMemsetAsync((void*)(dbuf + FLAG_OFF), 0,
                 (16 * 64 + 32) * sizeof(uint32_t), stream);

  lstm_persistent<<<dim3(256), dim3(256), 0, stream>>>(
      x, W_ih, W_hh, b_ih, b_hh, W_fc, b_fc, d_out, dbuf);
}

// Round 13
// 1002.901 us; speedup vs baseline: 1.6687x; 1.0515x over previous
//
#include <hip/hip_runtime.h>
#include <stdint.h>

// LSTM_Trend: B=256, T=512, F=64, H=512, P=24.
// Persistent kernel: 256 WGs x 256 threads (1/CU) = 16 batch-groups x 16
// hidden-groups. Weights register-resident as MFMA B-fragments.
//
// R13 = R12 resubmitted verbatim (R12's bench died in container acquisition
// -- infra, no kernel verdict; design re-audited: no deadlock, no race).
// R12 = R8's dataflow (coalesced bulk load -> frag-major LDS -> MFMA;
// flag poll; XCD-local sc0 stores verified by rendezvous, sc0sc1 loads
// hitting dirty local-L2 lines) with ONE barrier per step:
//  - A-tile DOUBLE-BUFFERED (2 x 19.6 KB): iter t reads buf[t&1], writes
//    h(t+1)+x(t+1) into buf[(t+1)&1]. The single loop-top __syncthreads
//    separates all writes (iter t) from all reads (iter t+1); barrier
//    drains lgkm+vm, so iter-(t-1) reads of buf[(t+1)&1] completed before
//    any wave rewrites it.
//  - act is WAVE-LOCAL (R10-proven numerics): wave wv acts on the units
//    its own MFMAs produce (WG-local units [wv*8,+8), all 16 rows) via a
//    wave-private Gw slice -- same-wave LDS write->read ordered by lgkmcnt
//    alone, no barrier. h store + wave vmcnt(0) drain + lane0 flag.
//  - per-lane poll (R10-proven): lane ln polls flag ln >= t+1; each wave
//    then bulk-loads ITS OWN 4 rows (coalesced ld128) and writes its
//    frag-major granules. No cross-wave join until next loop-top barrier.
// L2 overwrite safety: flag t+2 from a WG implies it passed S1(t+1) hence
// finished its bulk(t) loads of h(t+1); a producer observes all 64 flags
// >= t+2 at its poll(t+1) before act(t+2) overwrites h(t+1)'s parity.
// rule #18: sched_barrier(0) after inline-asm waitcnt with register-only
// consumers (poll compares, FC MFMAs). Fallback (rendezvous popcount!=1):
// sc0sc1 stores -- correct under any WG->XCD mapping, merely slower.

namespace {
constexpr int T_STEPS = 512;
constexpr int FEA  = 64;
constexpr int HID  = 512;
constexpr int NKI  = 18;          // 16 h k-iters + 2 x k-iters
constexpr int GWS  = 36;          // Gw row stride (floats), 16B-aligned reads
constexpr int GPITCH = 136;       // uint16 elems per granule (272 B pitch)
constexpr size_t HBUF_DW  = 256ull * 256;       // packed h dwords per parity
constexpr size_t FLAG_OFF = 2 * HBUF_DW;        // 16 groups x 64 wave-flags
constexpr size_t GRZ_OFF  = FLAG_OFF + 16 * 64; // gmask[16], gcnt[16]

typedef __bf16   bf16x8 __attribute__((ext_vector_type(8)));
typedef uint16_t u16x8  __attribute__((ext_vector_type(8)));
typedef float    f32x4  __attribute__((ext_vector_type(4)));
typedef uint32_t u32x4  __attribute__((ext_vector_type(4)));

union V8 { u16x8 u; bf16x8 b; u32x4 q; };

__device__ __forceinline__ float bf2f(uint16_t u) {
  union { uint32_t i; float f; } v; v.i = (uint32_t)u << 16; return v.f;
}
__device__ __forceinline__ uint16_t f2bf(float f) {
  union { float f; uint32_t i; } v; v.f = f;
  uint32_t x = v.i;
  return (uint16_t)((x + 0x7FFFu + ((x >> 16) & 1u)) >> 16);  // RNE
}
__device__ __forceinline__ float sigmoid_f(float x) {
  return 1.0f / (1.0f + __expf(-x));
}
__device__ __forceinline__ float tanh_f(float x) {
  float e = __expf(-2.0f * fabsf(x));
  float t = (1.0f - e) / (1.0f + e);
  return copysignf(t, x);
}
__device__ __forceinline__ bf16x8 load8(const void* base, size_t elem_off,
                                        bool fp32m) {
  V8 r;
  if (fp32m) {
    const float* p = (const float*)base + elem_off;
#pragma unroll
    for (int i = 0; i < 8; ++i) r.u[i] = f2bf(p[i]);
  } else {
    r.q = *(const u32x4*)((const uint16_t*)base + elem_off);
  }
  return r.b;
}
__device__ __forceinline__ float loadf(const void* base, int idx, bool fp32m) {
  return fp32m ? ((const float*)base)[idx] : bf2f(((const uint16_t*)base)[idx]);
}
__device__ __forceinline__ uint2 ldx4(const void* x, size_t elem_off,
                                      bool fp32m) {  // 4 x-vals -> 4 bf16
  if (fp32m) {
    float4 v = *(const float4*)((const float*)x + elem_off);
    uint2 w;
    w.x = (uint32_t)f2bf(v.x) | ((uint32_t)f2bf(v.y) << 16);
    w.y = (uint32_t)f2bf(v.z) | ((uint32_t)f2bf(v.w) << 16);
    return w;
  }
  return *(const uint2*)((const uint16_t*)x + elem_off);
}

// ---- exchange memory ops (transport proven in R4) -------------------------
__device__ __forceinline__ uint32_t ld32_sc01(const uint32_t* p) {
  uint32_t v;
  asm volatile("global_load_dword %0, %1, off sc0 sc1"
               : "=v"(v) : "v"(p) : "memory");
  return v;
}
__device__ __forceinline__ u32x4 ld128_sc01(const uint32_t* p) {
  u32x4 v;
  asm volatile("global_load_dwordx4 %0, %1, off sc0 sc1"
               : "=v"(v) : "v"(p) : "memory");
  return v;
}
__device__ __forceinline__ void st32_x(uint32_t* p, uint32_t v, bool xl) {
  if (xl) asm volatile("global_store_dword %0, %1, off sc0"
                       :: "v"(p), "v"(v) : "memory");
  else    asm volatile("global_store_dword %0, %1, off sc0 sc1"
                       :: "v"(p), "v"(v) : "memory");
}
__device__ __forceinline__ void waitcnt_vm0() {
  asm volatile("s_waitcnt vmcnt(0)" ::: "memory");
}
// rule #18: register-only consumers (compares/MFMA) get hoisted past an
// inline-asm waitcnt; sched_barrier(0) pins them.
__device__ __forceinline__ void waitcnt_vm0_fence() {
  asm volatile("s_waitcnt vmcnt(0)" ::: "memory");
  __builtin_amdgcn_sched_barrier(0);
}
} // namespace

__global__ __launch_bounds__(256, 1) void lstm_persistent(
    const void* __restrict__ x,      // [256][512][64]
    const void* __restrict__ W_ih,   // [2048][64]
    const void* __restrict__ W_hh,   // [2048][512]
    const void* __restrict__ b_ih,   // [2048]
    const void* __restrict__ b_hh,   // [2048]
    const void* __restrict__ W_fc,   // [1536][512]
    const void* __restrict__ b_fc,   // [1536]
    void* __restrict__ out,          // [256][1536]
    uint32_t* __restrict__ dbuf)     // ws: [2][256][256] h + flags + rdzv
{
  __shared__ __align__(16) uint16_t Als[2][72 * GPITCH];  // dbuf frag-major
  __shared__ float Gw[4][16 * GWS];     // wave-private gate slices
  __shared__ int   sflag, sok;

  const int tid = threadIdx.x;
  const int wv  = tid >> 6;              // wave 0..3
  const int ln  = tid & 63;
  const int nl  = ln & 15;               // MFMA m/n lane index (row)
  const int kq  = ln >> 4;               // MFMA k-quad
  const int bg  = blockIdx.x & 15;       // batch group
  const int wgi = blockIdx.x >> 4;       // hidden group 0..15
  const int r0  = bg * 16;               // first batch row of this group

  // ---- per-group XCD-identity rendezvous (one-time, R4-proven) ------------
  if (tid == 0) {
    uint32_t xcc;
    asm volatile("s_getreg_b32 %0, hwreg(HW_REG_XCC_ID)" : "=s"(xcc));
    unsigned* gmask = (unsigned*)(dbuf + GRZ_OFF) + bg;
    unsigned* gcnt  = (unsigned*)(dbuf + GRZ_OFF) + 16 + bg;
    atomicOr(gmask, 1u << (xcc & 31));
    __threadfence();
    atomicAdd(gcnt, 1u);
    while (atomicAdd(gcnt, 0u) < 16u) __builtin_amdgcn_s_sleep(1);
    __threadfence();
    unsigned m = atomicOr(gmask, 0u);
    sok = (__popc(m) == 1) ? 1 : 0;
  }

  // ---- dtype sniff (block-uniform): fp32 read as bf16 -> huge exponents
  if (tid == 1) sflag = 0;
  __syncthreads();
  {
    float a = fabsf(bf2f(((const uint16_t*)b_ih)[tid]));
    if (a > 1.0f) atomicOr(&sflag, 1);
  }
  __syncthreads();
  const bool fp32m = (sflag != 0);
  const bool xloc  = (sok != 0);

  // wave owns cols [wv*32, wv*32+32) as two 16-col subtiles sharing one A-frag
  bf16x8 breg[2][NKI];
  float  bias[2];
#pragma unroll
  for (int s = 0; s < 2; ++s) {
    int col  = wv * 32 + s * 16 + nl;    // 0..127
    int gate = col & 3;
    int unit = col >> 2;                 // 0..31
    int gcol = gate * HID + wgi * 32 + unit;
#pragma unroll
    for (int kk = 0; kk < NKI; ++kk) {
      int k0 = kk * 32 + kq * 8;
      if (k0 < HID)
        breg[s][kk] = load8(W_hh, (size_t)gcol * HID + k0, fp32m);
      else
        breg[s][kk] = load8(W_ih, (size_t)gcol * FEA + (k0 - HID), fp32m);
    }
    bias[s] = loadf(b_ih, gcol, fp32m) + loadf(b_hh, gcol, fp32m);
  }

  // wave-local act roles (R10-proven): row arow (0..15), unit-pair up (0..3);
  // wave wv acts on WG-local units wv*8 + up*2, +1 -> packed h dword:
  const int arow = ln >> 2;
  const int up   = ln & 3;
  const int hdw  = (r0 + arow) * 256 + wgi * 16 + wv * 4 + up;
  float c0 = 0.0f, c1 = 0.0f;

  // staging roles: row = tid>>4 (wave-aligned: rows 4wv..4wv+3), class sc
  const int srow = tid >> 4;
  const int sc   = tid & 15;

  uint32_t* flagw = dbuf + FLAG_OFF + bg * 64 + wgi * 4 + wv;   // producer
  const uint32_t* fbase = dbuf + FLAG_OFF + bg * 64;  // lane ln polls [ln]

  // ---- prologue: h(0)=0 in buf0 (granules 0..63), stage x(0) -> buf0 ----
  {
    u32x4 z = {0, 0, 0, 0};
    for (int i = tid; i < 64 * GPITCH / 8; i += 256)
      *(u32x4*)&Als[0][i * 8] = z;
  }
  {
    int gx = sc & 7, hf = sc >> 3;
    size_t off = (size_t)(r0 + srow) * (T_STEPS * FEA) + gx * 8 + hf * 4;
    uint2 w = ldx4(x, off, fp32m);
    *(uint2*)&Als[0][(64 + gx) * GPITCH + srow * 8 + hf * 4] = w;
  }

  for (int t = 0; t < T_STEPS; ++t) {
    __syncthreads();                     // the ONE barrier per step

    const uint16_t* Ar = &Als[t & 1][0];       // read buffer
    uint16_t*       Aw = &Als[(t + 1) & 1][0]; // write buffer

    // ---- gates = A @ W^T + bias: 18 ds_read_b128 + 36 MFMA ----
    f32x4 acc0, acc1;
    acc0[0] = bias[0]; acc0[1] = bias[0]; acc0[2] = bias[0]; acc0[3] = bias[0];
    acc1[0] = bias[1]; acc1[1] = bias[1]; acc1[2] = bias[1]; acc1[3] = bias[1];
#pragma unroll
    for (int kk = 0; kk < NKI; ++kk) {
      bf16x8 a = *(const bf16x8*)&Ar[(4 * kk + kq) * GPITCH + nl * 8];
      acc0 = __builtin_amdgcn_mfma_f32_16x16x32_bf16(a, breg[0][kk], acc0, 0, 0, 0);
      acc1 = __builtin_amdgcn_mfma_f32_16x16x32_bf16(a, breg[1][kk], acc1, 0, 0, 0);
    }

    // ---- gate scatter -> wave-private Gw (same-wave LDS, lgkmcnt only) ----
    float* G = &Gw[wv][0];
#pragma unroll
    for (int r = 0; r < 4; ++r) {
      G[(kq * 4 + r) * GWS + nl]      = acc0[r];
      G[(kq * 4 + r) * GWS + 16 + nl] = acc1[r];
    }

    const uint32_t tg = (uint32_t)(t + 1);
    const bool havex = (t + 1 < T_STEPS);

    // ---- act (wave-local gather); h store; WAVE drain; per-wave flag ----
    {
      const float* gp = &Gw[wv][arow * GWS + up * 8];
      f32x4 ga = *(const f32x4*)gp;
      f32x4 gb = *(const f32x4*)(gp + 4);
      c0 = sigmoid_f(ga[1]) * c0 + sigmoid_f(ga[0]) * tanh_f(ga[2]);
      float h0 = sigmoid_f(ga[3]) * tanh_f(c0);
      c1 = sigmoid_f(gb[1]) * c1 + sigmoid_f(gb[0]) * tanh_f(gb[2]);
      float h1 = sigmoid_f(gb[3]) * tanh_f(c1);
      uint32_t hp = (uint32_t)f2bf(h0) | ((uint32_t)f2bf(h1) << 16);
      st32_x(dbuf + (size_t)(tg & 1) * HBUF_DW + hdw, hp, xloc);
      waitcnt_vm0();                     // this wave's h store at L2
      if (ln == 0) st32_x(flagw, tg, xloc);
    }

    // ---- stage x(t+1) -> write buffer (overlaps flag/poll latency) ----
    if (havex) {
      int gx = sc & 7, hf = sc >> 3;
      size_t off = (size_t)(r0 + srow) * (T_STEPS * FEA)
                 + (size_t)(t + 1) * FEA + gx * 8 + hf * 4;
      uint2 w = ldx4(x, off, fp32m);
      *(uint2*)&Aw[(64 + gx) * GPITCH + srow * 8 + hf * 4] = w;
    }

    // ---- per-lane poll: lane ln waits flag[ln] >= t+1 (wave-independent) --
    for (;;) {
      uint32_t f = ld32_sc01(fbase + ln);
      waitcnt_vm0_fence();               // fence: compare is register-only
      if (f >= tg) break;
      __builtin_amdgcn_s_sleep(1);
    }

    // ---- bulk h(t+1): wave loads its own 4 rows -> frag-major granules ----
    {
      const uint32_t* src = dbuf + (size_t)(tg & 1) * HBUF_DW
                          + (size_t)(r0 + srow) * 256;
      u32x4 v0 = ld128_sc01(src + (sc + 0)  * 4);
      u32x4 v1 = ld128_sc01(src + (sc + 16) * 4);
      u32x4 v2 = ld128_sc01(src + (sc + 32) * 4);
      u32x4 v3 = ld128_sc01(src + (sc + 48) * 4);
      waitcnt_vm0();                     // LDS writes below (memory-ordered)
      *(u32x4*)&Aw[(sc + 0)  * GPITCH + srow * 8] = v0;
      *(u32x4*)&Aw[(sc + 16) * GPITCH + srow * 8] = v1;
      *(u32x4*)&Aw[(sc + 32) * GPITCH + srow * 8] = v2;
      *(u32x4*)&Aw[(sc + 48) * GPITCH + srow * 8] = v3;
    }
  }
  __syncthreads();                       // h_T resident in Als[0]

  // ---- FC head: out = h_T @ W_fc^T + b_fc (A-frags straight from LDS) ----
  int gwave = wgi * 4 + wv;              // 0..63 within the batch group
  for (int tile = gwave; tile < 96; tile += 64) {
    int n = tile * 16 + nl;              // out column
    float bs = loadf(b_fc, n, fp32m);
    f32x4 acc; acc[0] = bs; acc[1] = bs; acc[2] = bs; acc[3] = bs;
#pragma unroll
    for (int kk = 0; kk < 16; ++kk) {
      bf16x8 a = *(const bf16x8*)&Als[0][(4 * kk + kq) * GPITCH + nl * 8];
      bf16x8 b = load8(W_fc, (size_t)n * HID + kk * 32 + kq * 8, fp32m);
      acc = __builtin_amdgcn_mfma_f32_16x16x32_bf16(a, b, acc, 0, 0, 0);
    }
#pragma unroll
    for (int r = 0; r < 4; ++r) {
      int row = r0 + kq * 4 + r;
      if (fp32m) ((float*)out)[(size_t)row * 1536 + n] = acc[r];
      else       ((uint16_t*)out)[(size_t)row * 1536 + n] = f2bf(acc[r]);
    }
  }
}

extern "C" void kernel_launch(void* const* d_in, const int* in_sizes, int n_in,
                              void* d_out, int out_size, void* d_ws, size_t ws_size,
                              hipStream_t stream) {
  const void* x    = d_in[0];
  const void* W_ih = d_in[1];
  const void* W_hh = d_in[2];
  const void* b_ih = d_in[3];
  const void* b_hh = d_in[4];
  const void* W_fc = d_in[5];
  const void* b_fc = d_in[6];
  uint32_t* dbuf = (uint32_t*)d_ws;

  // flags (16x64 dwords) + rendezvous (gmask[16], gcnt[16]) start at 0 each
  // call (ws is poisoned 0xAA; poisoned gmask -> safe sc0sc1 fallback;
  // flags MUST be zeroed -- poll uses >= and poison would pass).
  hipMemsetAsync((void*)(dbuf + FLAG_OFF), 0,
                 (16 * 64 + 32) * sizeof(uint32_t), stream);

  lstm_persistent<<<dim3(256), dim3(256), 0, stream>>>(
      x, W_ih, W_hh, b_ih, b_hh, W_fc, b_fc, d_out, dbuf);
}